// Round 7
// baseline (90.353 us; speedup 1.0000x reference)
//
#include <hip/hip_runtime.h>
#include <hip/hip_cooperative_groups.h>
#include <math.h>

namespace cg = cooperative_groups;

#define NCOL 22
#define NEMB 12
#define D 64
#define BB 2048
#define NPAIR (NCOL*NCOL)   // 484
#define NBLK 512
#define REGC 0.001f

__device__ __forceinline__ float ftanh(float x) {
    float cx = fminf(fmaxf(x, -10.f), 10.f);
    float e = __expf(2.f * cx);
    return (e - 1.f) / (e + 1.f);
}

// ---------------------------------------------------------------------------
// One cooperative kernel, 512 blocks x 256 threads.
// Phase 1: blocks 0..483 build ptab[pair][144]; 484..505 column norms.
// grid.sync()
// Phase 2: every block gathers 4 batch elements over all 484 pairs.
// ---------------------------------------------------------------------------
__global__ __launch_bounds__(256) void k_fused(
    const int* __restrict__ features, const float* __restrict__ tables,
    const float* __restrict__ w1, const float* __restrict__ b1,
    const float* __restrict__ w2, const float* __restrict__ b2,
    const float* __restrict__ W_ops, const float* __restrict__ W_concat,
    const float* __restrict__ aw,
    float2* __restrict__ ptab, float* __restrict__ cn,
    float* __restrict__ out)
{
    __shared__ float ti[NEMB * 65];
    __shared__ float tj[NEMB * 65];
    __shared__ float4 w4s[D];
    __shared__ float wls[2 * D];
    __shared__ int   fs[NCOL][4];
    __shared__ float red[64][4][2];

    int bid = blockIdx.x, tid = threadIdx.x;

    // ======================= PHASE 1 =======================
    if (bid < NPAIR) {
        int i = bid / NCOL, j = bid - (bid / NCOL) * NCOL;
        bool diag = (i == j);
        float b2v = b2[0];
        float a0 = aw[0], a1 = aw[1], a2 = aw[2], a3 = aw[3], a4 = aw[4];
        const float* Wm   = W_ops + 1 * NPAIR * 2 * D;
        const float* Wmax = W_ops + 2 * NPAIR * 2 * D;
        const float* Wmin = W_ops + 3 * NPAIR * 2 * D;

        // stage trans rows i and j, computed inline (6 MLP evals/thread)
        for (int k = tid; k < 2 * NEMB * D; k += 256) {
            int half = (k >= NEMB * D);
            int kk = k - half * NEMB * D;
            float x = tables[(half ? j : i) * NEMB * D + kk];
            float acc = b2v;
            #pragma unroll
            for (int h = 0; h < 8; ++h)
                acc = fmaf(ftanh(fmaf(x, w1[h], b1[h])), w2[h], acc);
            (half ? tj : ti)[(kk >> 6) * 65 + (kk & 63)] = acc;
        }

        if (tid < D) {
            int i0 = (bid * 2 + 0) * D + tid;
            int i1 = (bid * 2 + 1) * D + tid;
            float4 v;
            v.x = a1 * Wm[i0];
            v.y = a1 * Wm[i1];
            v.z = 0.5f * (a2 * Wmax[i0] - a3 * Wmin[i0]);
            v.w = 0.5f * (a2 * Wmax[i1] - a3 * Wmin[i1]);
            w4s[tid] = v;
        }

        if (diag && tid >= 128 && tid < 256) {
            int t = tid - 128;
            int o = t >> 6, d = t & 63;
            float lp = 0.f, lc = 0.f, lmm = 0.f;
            #pragma unroll
            for (int jj = 0; jj < NCOL; ++jj) {
                int ij = ((i * NCOL + jj) * 2 + o) * D + d;
                int ji = ((jj * NCOL + i) * 2 + o) * D + d;
                lp += W_ops[ij] + W_ops[ji];
                lc += W_concat[((i * NCOL + jj) * 2 + o) * 2 * D + d]
                    + W_concat[((jj * NCOL + i) * 2 + o) * 2 * D + D + d];
                lmm += a2 * (Wmax[ij] + Wmax[ji]) + a3 * (Wmin[ij] + Wmin[ji]);
            }
            wls[t] = a0 * lp + a4 * lc + 0.5f * lmm;
        }
        __syncthreads();

        if (tid < NEMB * NEMB) {
            int ei = tid / NEMB, ej = tid - ei * NEMB;
            float r0 = 0.f, r1 = 0.f, l0 = 0.f, l1 = 0.f;
            #pragma unroll 8
            for (int d = 0; d < D; ++d) {
                float a = ti[ei * 65 + d], b = tj[ej * 65 + d];
                float4 w4 = w4s[d];
                float pp = a * b, dd = fabsf(a - b);
                r0 = fmaf(pp, w4.x, fmaf(dd, w4.z, r0));
                r1 = fmaf(pp, w4.y, fmaf(dd, w4.w, r1));
                if (diag & (ei == ej)) {
                    l0 = fmaf(a, wls[d], l0);
                    l1 = fmaf(a, wls[D + d], l1);
                }
            }
            ptab[bid * 144 + tid] = make_float2(r0 + l0, r1 + l1);
        }
    } else if (bid < NPAIR + NCOL) {            // ---- column norms ----
        int i = bid - NPAIR;
        // reuse ti[] as ssq[12], wls[] as parts[4]
        if (tid < NEMB) {
            const float* tp = tables + (i * NEMB + tid) * D;
            float s = 0.f;
            #pragma unroll
            for (int d = 0; d < D; ++d) s = fmaf(tp[d], tp[d], s);
            ti[tid] = s;
        }
        __syncthreads();
        float s = 0.f;
        for (int k = tid; k < BB; k += 256) s += ti[features[i * BB + k]];
        #pragma unroll
        for (int m = 32; m; m >>= 1) s += __shfl_xor(s, m);
        if ((tid & 63) == 0) wls[tid >> 6] = s;
        __syncthreads();
        if (tid == 0)
            cn[i] = sqrtf(wls[0] + wls[1] + wls[2] + wls[3]);
    }

    cg::this_grid().sync();

    // ======================= PHASE 2 =======================
    int b0 = bid * 4;
    if (tid < NCOL * 4) {
        int i = tid >> 2, q = tid & 3;
        fs[i][q] = features[i * BB + b0 + q];
    }
    __syncthreads();

    int b = tid & 3, g = tid >> 2;              // 64 pair-groups x 4 b's
    int p0 = (g * NPAIR) >> 6, p1 = ((g + 1) * NPAIR) >> 6;
    float a0 = 0.f, a1 = 0.f;
    #pragma unroll 4
    for (int p = p0; p < p1; ++p) {
        int i = (p * 2979) >> 16;               // exact p/22 for p < 484
        int j = p - i * NCOL;
        float2 v = ptab[p * 144 + fs[i][b] * NEMB + fs[j][b]];
        a0 += v.x; a1 += v.y;
    }
    red[g][b][0] = a0;
    red[g][b][1] = a1;
    __syncthreads();
    if (tid < 8) {
        int bb = tid >> 1, o = tid & 1;
        float s = 0.f;
        #pragma unroll
        for (int g2 = 0; g2 < 64; ++g2) s += red[g2][bb][o];
        out[(b0 + bb) * 2 + o] = s;
    }
    if (bid == 0 && tid == 192) {
        float s = 0.f;
        for (int c = 0; c < NCOL; ++c) s += cn[c];
        out[BB * 2] = REGC * (2.0f * NCOL) * s;
    }
}

extern "C" void kernel_launch(void* const* d_in, const int* in_sizes, int n_in,
                              void* d_out, int out_size, void* d_ws, size_t ws_size,
                              hipStream_t stream) {
    const int*   features = (const int*)d_in[0];
    const float* tables   = (const float*)d_in[1];
    const float* w1       = (const float*)d_in[2];
    const float* b1       = (const float*)d_in[3];
    const float* w2       = (const float*)d_in[4];
    const float* b2       = (const float*)d_in[5];
    const float* W_ops    = (const float*)d_in[6];
    const float* W_concat = (const float*)d_in[7];
    const float* aw       = (const float*)d_in[8];
    float* out = (float*)d_out;
    float* ws  = (float*)d_ws;

    float2* ptab = (float2*)ws;                       // 484*144 f2 = 557,568 B
    float*  cn   = ws + 2 * NPAIR * 144;              // 22 f

    void* args[] = { &features, &tables, &w1, &b1, &w2, &b2,
                     &W_ops, &W_concat, &aw, &ptab, &cn, &out };
    hipLaunchCooperativeKernel((void*)k_fused, dim3(NBLK), dim3(256),
                               args, 0, stream);
}

// Round 8
// 25.876 us; speedup vs baseline: 3.4918x; 3.4918x over previous
//
#include <hip/hip_runtime.h>
#include <math.h>

#define NCOL 22
#define NEMB 12
#define D 64
#define BB 2048
#define NPAIR (NCOL*NCOL)   // 484
#define REGC 0.001f

__device__ __forceinline__ float ftanh(float x) {
    float cx = fminf(fmaxf(x, -10.f), 10.f);
    float e = __expf(2.f * cx);
    return (e - 1.f) / (e + 1.f);
}

// ---------------------------------------------------------------------------
// k_build: blocks 0..483 — one per pair (i,j). Recompute the two trans rows
// inline, pack pair weights, diagonal blocks fold the linear weights, then
// 144 threads emit the (ei,ej) table. Blocks 484..505 — column norms.
// (identical to the round-6 passing version)
// ---------------------------------------------------------------------------
__global__ __launch_bounds__(256) void k_build(
    const int* __restrict__ features, const float* __restrict__ tables,
    const float* __restrict__ w1, const float* __restrict__ b1,
    const float* __restrict__ w2, const float* __restrict__ b2,
    const float* __restrict__ W_ops, const float* __restrict__ W_concat,
    const float* __restrict__ aw,
    float2* __restrict__ ptab, float* __restrict__ cn)
{
    int bid = blockIdx.x, tid = threadIdx.x;

    if (bid >= NPAIR) {                 // ---- column-norm blocks ----
        int i = bid - NPAIR;
        __shared__ float ssq[NEMB];
        __shared__ float parts[4];
        if (tid < NEMB) {
            const float* tp = tables + (i * NEMB + tid) * D;
            float s = 0.f;
            #pragma unroll
            for (int d = 0; d < D; ++d) s = fmaf(tp[d], tp[d], s);
            ssq[tid] = s;
        }
        __syncthreads();
        float s = 0.f;
        for (int k = tid; k < BB; k += 256) s += ssq[features[i * BB + k]];
        #pragma unroll
        for (int m = 32; m; m >>= 1) s += __shfl_xor(s, m);
        if ((tid & 63) == 0) parts[tid >> 6] = s;
        __syncthreads();
        if (tid == 0)
            cn[i] = sqrtf(parts[0] + parts[1] + parts[2] + parts[3]);
        return;
    }

    // ---- pair blocks ----
    int i = bid / NCOL, j = bid - (bid / NCOL) * NCOL;
    bool diag = (i == j);
    __shared__ float ti[NEMB * 65];
    __shared__ float tj[NEMB * 65];
    __shared__ float4 w4s[D];
    __shared__ float wls[2 * D];

    float b2v = b2[0];
    float a0 = aw[0], a1 = aw[1], a2 = aw[2], a3 = aw[3], a4 = aw[4];
    const float* Wm   = W_ops + 1 * NPAIR * 2 * D;
    const float* Wmax = W_ops + 2 * NPAIR * 2 * D;
    const float* Wmin = W_ops + 3 * NPAIR * 2 * D;

    for (int k = tid; k < 2 * NEMB * D; k += 256) {
        int half = (k >= NEMB * D);
        int kk = k - half * NEMB * D;
        float x = tables[(half ? j : i) * NEMB * D + kk];
        float acc = b2v;
        #pragma unroll
        for (int h = 0; h < 8; ++h)
            acc = fmaf(ftanh(fmaf(x, w1[h], b1[h])), w2[h], acc);
        (half ? tj : ti)[(kk >> 6) * 65 + (kk & 63)] = acc;
    }

    if (tid < D) {
        int i0 = (bid * 2 + 0) * D + tid;
        int i1 = (bid * 2 + 1) * D + tid;
        float4 v;
        v.x = a1 * Wm[i0];
        v.y = a1 * Wm[i1];
        v.z = 0.5f * (a2 * Wmax[i0] - a3 * Wmin[i0]);
        v.w = 0.5f * (a2 * Wmax[i1] - a3 * Wmin[i1]);
        w4s[tid] = v;
    }

    if (diag && tid >= 128 && tid < 256) {
        int t = tid - 128;
        int o = t >> 6, d = t & 63;
        float lp = 0.f, lc = 0.f, lmm = 0.f;
        #pragma unroll
        for (int jj = 0; jj < NCOL; ++jj) {
            int ij = ((i * NCOL + jj) * 2 + o) * D + d;
            int ji = ((jj * NCOL + i) * 2 + o) * D + d;
            lp += W_ops[ij] + W_ops[ji];
            lc += W_concat[((i * NCOL + jj) * 2 + o) * 2 * D + d]
                + W_concat[((jj * NCOL + i) * 2 + o) * 2 * D + D + d];
            lmm += a2 * (Wmax[ij] + Wmax[ji]) + a3 * (Wmin[ij] + Wmin[ji]);
        }
        wls[t] = a0 * lp + a4 * lc + 0.5f * lmm;
    }
    __syncthreads();

    if (tid < NEMB * NEMB) {
        int ei = tid / NEMB, ej = tid - ei * NEMB;
        float r0 = 0.f, r1 = 0.f, l0 = 0.f, l1 = 0.f;
        #pragma unroll 8
        for (int d = 0; d < D; ++d) {
            float a = ti[ei * 65 + d], b = tj[ej * 65 + d];
            float4 w4 = w4s[d];
            float pp = a * b, dd = fabsf(a - b);
            r0 = fmaf(pp, w4.x, fmaf(dd, w4.z, r0));
            r1 = fmaf(pp, w4.y, fmaf(dd, w4.w, r1));
            if (diag & (ei == ej)) {
                l0 = fmaf(a, wls[d], l0);
                l1 = fmaf(a, wls[D + d], l1);
            }
        }
        ptab[bid * 144 + tid] = make_float2(r0 + l0, r1 + l1);
    }
}

// ---------------------------------------------------------------------------
// k_part: 512 blocks = 32 b-groups x 16 pair-groups. lane = b (64 b's/block).
// Wave w walks the pairs of global group g = pg*4+w (~7-8 pairs) SERIALLY and
// UNIFORMLY: all 64 lanes read inside one pair's 1152B table per step.
// Each wave writes its own float2 partial row — unique writer, coalesced.
// ---------------------------------------------------------------------------
__global__ __launch_bounds__(256) void k_part(const int* __restrict__ features,
        const float2* __restrict__ ptab, float2* __restrict__ partial)
{
    __shared__ int fs[NCOL][64];
    int tid = threadIdx.x;
    int w = tid >> 6, lane = tid & 63;
    int bg = blockIdx.x >> 4, pg = blockIdx.x & 15;
    int b0 = bg * 64;

    for (int k = tid; k < NCOL * 64; k += 256) {
        int i = k >> 6, l = k & 63;
        fs[i][l] = features[i * BB + b0 + l];
    }
    __syncthreads();

    int g = pg * 4 + w;                       // [0,64)
    int p0 = (g * NPAIR) >> 6, p1 = ((g + 1) * NPAIR) >> 6;
    float a0 = 0.f, a1 = 0.f;
    #pragma unroll 2
    for (int p = p0; p < p1; ++p) {
        int i = (p * 2979) >> 16;             // exact p/22 for p < 484
        int j = p - i * NCOL;
        float2 v = ptab[p * 144 + fs[i][lane] * NEMB + fs[j][lane]];
        a0 += v.x; a1 += v.y;
    }
    partial[g * BB + b0 + lane] = make_float2(a0, a1);
}

// ---------------------------------------------------------------------------
// k_final: blocks 0..7 — thread b sums the 64 group-partials (coalesced) and
// writes out[b*2 .. b*2+1]. Block 8 — reg scalar from cn.
// ---------------------------------------------------------------------------
__global__ __launch_bounds__(256) void k_final(const float2* __restrict__ partial,
        const float* __restrict__ cn, float* __restrict__ out)
{
    int bid = blockIdx.x, tid = threadIdx.x;
    if (bid < 8) {
        int b = bid * 256 + tid;
        float s0 = 0.f, s1 = 0.f;
        #pragma unroll 8
        for (int g = 0; g < 64; ++g) {
            float2 v = partial[g * BB + b];
            s0 += v.x; s1 += v.y;
        }
        out[b * 2 + 0] = s0;
        out[b * 2 + 1] = s1;
    } else if (tid == 0) {
        float s = 0.f;
        for (int c = 0; c < NCOL; ++c) s += cn[c];
        out[BB * 2] = REGC * (2.0f * NCOL) * s;
    }
}

extern "C" void kernel_launch(void* const* d_in, const int* in_sizes, int n_in,
                              void* d_out, int out_size, void* d_ws, size_t ws_size,
                              hipStream_t stream) {
    const int*   features = (const int*)d_in[0];
    const float* tables   = (const float*)d_in[1];
    const float* w1       = (const float*)d_in[2];
    const float* b1       = (const float*)d_in[3];
    const float* w2       = (const float*)d_in[4];
    const float* b2       = (const float*)d_in[5];
    const float* W_ops    = (const float*)d_in[6];
    const float* W_concat = (const float*)d_in[7];
    const float* aw       = (const float*)d_in[8];
    float* out = (float*)d_out;
    char*  ws  = (char*)d_ws;

    float2* ptab    = (float2*)ws;                     // 484*144*8 = 557,568 B
    float*  cn      = (float*)(ws + 557568);           // 22 f
    float2* partial = (float2*)(ws + 557568 + 128);    // 64*2048*8 = 1,048,576 B

    k_build<<<dim3(NPAIR + NCOL), dim3(256), 0, stream>>>(
        features, tables, w1, b1, w2, b2, W_ops, W_concat, aw, ptab, cn);
    k_part <<<dim3(512), dim3(256), 0, stream>>>(features, ptab, partial);
    k_final<<<dim3(9),   dim3(256), 0, stream>>>(partial, cn, out);
}

// Round 9
// 20.053 us; speedup vs baseline: 4.5057x; 1.2904x over previous
//
#include <hip/hip_runtime.h>
#include <math.h>

#define NCOL 22
#define NEMB 12
#define D 64
#define BB 2048
#define NPAIR (NCOL*NCOL)   // 484
#define REGC 0.001f

__device__ __forceinline__ float ftanh(float x) {
    float cx = fminf(fmaxf(x, -10.f), 10.f);
    float e = __expf(2.f * cx);
    return (e - 1.f) / (e + 1.f);
}

// ---------------------------------------------------------------------------
// k_build: 384 threads. Blocks 0..483 — one per pair (i,j):
//   stage trans rows (4 MLP evals/thread), pack pair weights, diag blocks
//   fold linear weights, then 288 threads = 144 combos x 2 d-halves compute
//   32-deep partial sums, combined via LDS. Blocks 484..505 — column norms.
// ---------------------------------------------------------------------------
__global__ __launch_bounds__(384) void k_build(
    const int* __restrict__ features, const float* __restrict__ tables,
    const float* __restrict__ w1, const float* __restrict__ b1,
    const float* __restrict__ w2, const float* __restrict__ b2,
    const float* __restrict__ W_ops, const float* __restrict__ W_concat,
    const float* __restrict__ aw,
    float2* __restrict__ ptab, float* __restrict__ cn)
{
    int bid = blockIdx.x, tid = threadIdx.x;

    if (bid >= NPAIR) {                 // ---- column-norm blocks ----
        int i = bid - NPAIR;
        __shared__ float ssq[NEMB];
        __shared__ float parts[6];
        if (tid < NEMB) {
            const float* tp = tables + (i * NEMB + tid) * D;
            float s = 0.f;
            #pragma unroll
            for (int d = 0; d < D; ++d) s = fmaf(tp[d], tp[d], s);
            ssq[tid] = s;
        }
        __syncthreads();
        float s = 0.f;
        for (int k = tid; k < BB; k += 384) s += ssq[features[i * BB + k]];
        #pragma unroll
        for (int m = 32; m; m >>= 1) s += __shfl_xor(s, m);
        if ((tid & 63) == 0) parts[tid >> 6] = s;
        __syncthreads();
        if (tid == 0) {
            float t = 0.f;
            #pragma unroll
            for (int q = 0; q < 6; ++q) t += parts[q];
            cn[i] = sqrtf(t);
        }
        return;
    }

    // ---- pair blocks ----
    int i = bid / NCOL, j = bid - (bid / NCOL) * NCOL;
    bool diag = (i == j);
    __shared__ float ti[NEMB * 65];
    __shared__ float tj[NEMB * 65];
    __shared__ float4 w4s[D];
    __shared__ float wls[2 * D];
    __shared__ float2 comb[144][2];

    float b2v = b2[0];
    float a0 = aw[0], a1 = aw[1], a2 = aw[2], a3 = aw[3], a4 = aw[4];
    const float* Wm   = W_ops + 1 * NPAIR * 2 * D;
    const float* Wmax = W_ops + 2 * NPAIR * 2 * D;
    const float* Wmin = W_ops + 3 * NPAIR * 2 * D;

    // stage trans rows i and j (4 MLP evals per thread)
    for (int k = tid; k < 2 * NEMB * D; k += 384) {
        int half = (k >= NEMB * D);
        int kk = k - half * NEMB * D;
        float x = tables[(half ? j : i) * NEMB * D + kk];
        float acc = b2v;
        #pragma unroll
        for (int h = 0; h < 8; ++h)
            acc = fmaf(ftanh(fmaf(x, w1[h], b1[h])), w2[h], acc);
        (half ? tj : ti)[(kk >> 6) * 65 + (kk & 63)] = acc;
    }

    // pack pair weights (threads 0..63)
    if (tid < D) {
        int i0 = (bid * 2 + 0) * D + tid;
        int i1 = (bid * 2 + 1) * D + tid;
        float4 v;
        v.x = a1 * Wm[i0];
        v.y = a1 * Wm[i1];
        v.z = 0.5f * (a2 * Wmax[i0] - a3 * Wmin[i0]);
        v.w = 0.5f * (a2 * Wmax[i1] - a3 * Wmin[i1]);
        w4s[tid] = v;
    }

    // diagonal blocks fold the linear weights (threads 64..191)
    if (diag && tid >= 64 && tid < 192) {
        int t = tid - 64;
        int o = t >> 6, d = t & 63;
        float lp = 0.f, lc = 0.f, lmm = 0.f;
        #pragma unroll
        for (int jj = 0; jj < NCOL; ++jj) {
            int ij = ((i * NCOL + jj) * 2 + o) * D + d;
            int ji = ((jj * NCOL + i) * 2 + o) * D + d;
            lp += W_ops[ij] + W_ops[ji];
            lc += W_concat[((i * NCOL + jj) * 2 + o) * 2 * D + d]
                + W_concat[((jj * NCOL + i) * 2 + o) * 2 * D + D + d];
            lmm += a2 * (Wmax[ij] + Wmax[ji]) + a3 * (Wmin[ij] + Wmin[ji]);
        }
        wls[t] = a0 * lp + a4 * lc + 0.5f * lmm;
    }
    __syncthreads();

    // combos: 288 threads = 144 combos x 2 halves of d
    if (tid < 288) {
        int c = tid >> 1, half = tid & 1;
        int ei = c / NEMB, ej = c - (c / NEMB) * NEMB;
        int d0 = half * 32;
        float r0 = 0.f, r1 = 0.f, l0 = 0.f, l1 = 0.f;
        bool dl = diag & (ei == ej);
        #pragma unroll 8
        for (int d = d0; d < d0 + 32; ++d) {
            float a = ti[ei * 65 + d], b = tj[ej * 65 + d];
            float4 w4 = w4s[d];
            float pp = a * b, dd = fabsf(a - b);
            r0 = fmaf(pp, w4.x, fmaf(dd, w4.z, r0));
            r1 = fmaf(pp, w4.y, fmaf(dd, w4.w, r1));
            if (dl) {
                l0 = fmaf(a, wls[d], l0);
                l1 = fmaf(a, wls[D + d], l1);
            }
        }
        comb[c][half] = make_float2(r0 + l0, r1 + l1);
    }
    __syncthreads();
    if (tid < 144) {
        float2 u = comb[tid][0], v = comb[tid][1];
        ptab[bid * 144 + tid] = make_float2(u.x + v.x, u.y + v.y);
    }
}

// ---------------------------------------------------------------------------
// k_gather: 512 blocks x 4 b's (2 blocks/CU). Thread (g,b): g = tid>>2 in
// [0,64) sums ~8 pairs for batch element b; wave-shuffle reduce over the 16
// g's in each wave, LDS reduce over 4 waves; single writer per output.
// Block 0 also writes the reg scalar.
// ---------------------------------------------------------------------------
__global__ __launch_bounds__(256) void k_gather(const int* __restrict__ features,
        const float2* __restrict__ ptab, const float* __restrict__ cn,
        float* __restrict__ out)
{
    __shared__ int fs[NCOL][4];
    __shared__ float red[4][4][2];
    int tid = threadIdx.x;
    int b0 = blockIdx.x * 4;

    if (tid < NCOL * 4) {
        int i = tid >> 2, q = tid & 3;
        fs[i][q] = features[i * BB + b0 + q];
    }
    __syncthreads();

    int b = tid & 3, g = tid >> 2;              // 64 pair-groups x 4 b's
    int p0 = (g * NPAIR) >> 6, p1 = ((g + 1) * NPAIR) >> 6;
    float a0 = 0.f, a1 = 0.f;
    #pragma unroll 2
    for (int p = p0; p < p1; ++p) {
        int i = (p * 2979) >> 16;               // exact p/22 for p < 484
        int j = p - i * NCOL;
        float2 v = ptab[p * 144 + fs[i][b] * NEMB + fs[j][b]];
        a0 += v.x; a1 += v.y;
    }
    // reduce the 16 g's within each wave (lanes differing in bits 2..5)
    #pragma unroll
    for (int m = 4; m <= 32; m <<= 1) {
        a0 += __shfl_xor(a0, m);
        a1 += __shfl_xor(a1, m);
    }
    int w = tid >> 6, lane = tid & 63;
    if (lane < 4) {
        red[w][lane][0] = a0;
        red[w][lane][1] = a1;
    }
    __syncthreads();
    if (tid < 8) {
        int bb = tid >> 1, o = tid & 1;
        out[(b0 + bb) * 2 + o] = red[0][bb][o] + red[1][bb][o]
                               + red[2][bb][o] + red[3][bb][o];
    }
    if (blockIdx.x == 0 && tid == 64) {
        float s = 0.f;
        for (int c = 0; c < NCOL; ++c) s += cn[c];
        out[BB * 2] = REGC * (2.0f * NCOL) * s;
    }
}

extern "C" void kernel_launch(void* const* d_in, const int* in_sizes, int n_in,
                              void* d_out, int out_size, void* d_ws, size_t ws_size,
                              hipStream_t stream) {
    const int*   features = (const int*)d_in[0];
    const float* tables   = (const float*)d_in[1];
    const float* w1       = (const float*)d_in[2];
    const float* b1       = (const float*)d_in[3];
    const float* w2       = (const float*)d_in[4];
    const float* b2       = (const float*)d_in[5];
    const float* W_ops    = (const float*)d_in[6];
    const float* W_concat = (const float*)d_in[7];
    const float* aw       = (const float*)d_in[8];
    float* out = (float*)d_out;
    char*  ws  = (char*)d_ws;

    float2* ptab = (float2*)ws;                     // 484*144*8 = 557,568 B
    float*  cn   = (float*)(ws + 557568);           // 22 f

    k_build <<<dim3(NPAIR + NCOL), dim3(384), 0, stream>>>(
        features, tables, w1, b1, w2, b2, W_ops, W_concat, aw, ptab, cn);
    k_gather<<<dim3(512), dim3(256), 0, stream>>>(features, ptab, cn, out);
}